// Round 15
// baseline (166.834 us; speedup 1.0000x reference)
//
#include <hip/hip_runtime.h>
#include <math.h>

#define HEADS 8
#define HID 256
#define INC 128
#define GDIM 2048  // HEADS*HID
#define NEG_SLOPE 0.2f
#define KSPLIT 2

typedef unsigned short ushort_t;
typedef short bf16x8 __attribute__((ext_vector_type(8)));
typedef ushort_t u16x8 __attribute__((ext_vector_type(8)));
typedef float f32x4 __attribute__((ext_vector_type(4)));

__device__ __forceinline__ ushort_t f2bf(float f) {
  union { float f; unsigned u; } v; v.f = f;
  unsigned r = (v.u + 0x7FFF + ((v.u >> 16) & 1)) >> 16;  // RTNE
  return (ushort_t)r;
}
__device__ __forceinline__ float bf2f(ushort_t u) {
  union { unsigned u; float f; } v; v.u = ((unsigned)u) << 16;
  return v.f;
}

__device__ __forceinline__ void gload_lds16(const ushort_t* g, ushort_t* l) {
  __builtin_amdgcn_global_load_lds(
      (const __attribute__((address_space(1))) unsigned int*)g,
      (__attribute__((address_space(3))) unsigned int*)l, 16, 0, 0);
}

// LDS chunk swizzle (verified r4/r5: SQ_LDS_BANK_CONFLICT -> 0)
__device__ __forceinline__ int src_chunk(int lane) {
  return ((lane & 3) - ((lane >> 3) & 3)) & 3;
}
__device__ __forceinline__ int rd_chunk(int lc, int kg) {
  return (kg + ((lc >> 1) & 3)) & 3;
}

// ---------------- custom zero (replaces pathological runtime blit) ----------------
__global__ __launch_bounds__(256) void zero_deg(int* __restrict__ deg, int n)
{
  int i = blockIdx.x * 256 + threadIdx.x;
  if (i < n) deg[i] = 0;
}

// ---------------- fused prep: x->bf16, 3 weight transposes, deg_count, wtilde ----------------
__global__ __launch_bounds__(256) void prep(
    const float* __restrict__ x, ushort_t* __restrict__ xb,
    const float* __restrict__ Wg, ushort_t* __restrict__ WgT,
    const float* __restrict__ Wl, const float* __restrict__ Wr, ushort_t* __restrict__ WsT,
    const int* __restrict__ ei, int* __restrict__ deg, int E,
    const float* __restrict__ att_s, const float* __restrict__ att_d, float* __restrict__ wt,
    int o1, int o2, int o3, int o4, int o5)
{
  __shared__ float tile[32][33];
  __shared__ float attl[256];
  int b = blockIdx.x, t = threadIdx.x;
  if (b < o1) {
    int i = b * 1024 + t * 4;
    float4 v = *(const float4*)(x + i);
    ushort_t o[4] = {f2bf(v.x), f2bf(v.y), f2bf(v.z), f2bf(v.w)};
    *(unsigned long long*)(xb + i) = *(unsigned long long*)o;
  } else if (b < o4) {
    const float* src; ushort_t* dst; int R, C, rowOff, bx, by;
    if (b < o2)      { int idx = b - o1; src = Wg; dst = WgT; R = INC;  C = GDIM; rowOff = 0;   bx = idx % (INC / 32);  by = idx / (INC / 32); }
    else if (b < o3) { int idx = b - o2; src = Wl; dst = WsT; R = GDIM; C = HID;  rowOff = 0;   bx = idx % (GDIM / 32); by = idx / (GDIM / 32); }
    else             { int idx = b - o3; src = Wr; dst = WsT; R = GDIM; C = HID;  rowOff = HID; bx = idx % (GDIM / 32); by = idx / (GDIM / 32); }
    int tx = t & 31, ty = t >> 5;
    int r0 = bx * 32, c0 = by * 32;
    #pragma unroll
    for (int i = 0; i < 32; i += 8)
      tile[ty + i][tx] = src[(size_t)(r0 + ty + i) * C + c0 + tx];
    __syncthreads();
    #pragma unroll
    for (int i = 0; i < 32; i += 8)
      dst[(size_t)(rowOff + c0 + ty + i) * R + r0 + tx] = f2bf(tile[tx][ty + i]);
  } else if (b < o5) {
    int e = (b - o4) * 256 + t;
    if (e < E) atomicAdd(&deg[ei[E + e]], 1);
  } else {
    int j = b - o5;                 // 0..15
    int hd = j & 7;
    const float* att = (j < 8) ? att_s : att_d;
    if (t < 256) attl[t] = att[hd * 256 + t];
    __syncthreads();
    if (t < 128) {
      float acc = 0.f;
      #pragma unroll 8
      for (int c = 0; c < 256; ++c)
        acc += Wg[(size_t)t * GDIM + hd * 256 + c] * attl[c];
      wt[j * 128 + t] = acc;
    }
  }
}

// ---------------- a_all[n][16] = xb[n] . wt[j] ----------------
__global__ __launch_bounds__(256) void a_dots(
    const ushort_t* __restrict__ xb, const float* __restrict__ wt,
    float* __restrict__ a_all, int N)
{
  __shared__ float wts[16][132];
  __shared__ ushort_t xs[16 * 128];
  int t = threadIdx.x;
  for (int i = t; i < 2048; i += 256) wts[i >> 7][i & 127] = wt[i];
  int b0 = blockIdx.x * 16;
  {
    int row = t >> 4, off = (t & 15) * 8;
    int n = b0 + row; if (n >= N) n = N - 1;
    *(u16x8*)&xs[row * 128 + off] = *(const u16x8*)(xb + (size_t)n * 128 + off);
  }
  __syncthreads();
  int nl = t >> 4, j = t & 15;
  float acc = 0.f;
  #pragma unroll 8
  for (int k = 0; k < 128; ++k)
    acc += bf2f(xs[nl * 128 + k]) * wts[j][k];
  int n = b0 + nl;
  if (n < N) a_all[(size_t)n * 16 + j] = acc;
}

// ---------------- CSR scan over deg[N] (40 KB), 1024 threads ----------------
__global__ __launch_bounds__(1024) void scan_deg(const int* __restrict__ deg, int* __restrict__ start,
                                                 int* __restrict__ cursor, int N)
{
  __shared__ int sums[1024];
  int t = threadIdx.x;
  int chunk = (N + 1023) / 1024;
  int s = 0;
  for (int i = 0; i < chunk; ++i) {
    int idx = t * chunk + i;
    if (idx < N) s += deg[idx];
  }
  sums[t] = s;
  __syncthreads();
  for (int off = 1; off < 1024; off <<= 1) {
    int v = (t >= off) ? sums[t - off] : 0;
    __syncthreads();
    sums[t] += v;
    __syncthreads();
  }
  int run = (t == 0) ? 0 : sums[t - 1];
  for (int i = 0; i < chunk; ++i) {
    int idx = t * chunk + i;
    if (idx < N) { start[idx] = run; cursor[idx] = run; run += deg[idx]; }
  }
}

__global__ void fill_buckets(const int* __restrict__ ei, int* __restrict__ cursor,
                             int* __restrict__ srcs, int E)
{
  int e = blockIdx.x * 256 + threadIdx.x;
  if (e < E) {
    int n = ei[E + e];
    int p = atomicAdd(&cursor[n], 1);
    srcs[p] = ei[e];
  }
}

// ---------------- GAT softmax + x-space aggregate -> aggb[N][8][128] bf16 ----------------
__global__ __launch_bounds__(256) void gat_aggregate(
    const ushort_t* __restrict__ xb, const float* __restrict__ a_all,
    const int* __restrict__ start, const int* __restrict__ deg,
    const int* __restrict__ srcs, ushort_t* __restrict__ aggb, int N)
{
  int n = blockIdx.x, t = threadIdx.x;
  __shared__ float adst[8];
  __shared__ float emax[8];
  __shared__ float esum[8];
  __shared__ float red[256];
  __shared__ float alpha_s[32][8];
  __shared__ int src_s[32];
  int cnt = deg[n];
  int base = start[n];
  if (t < 8) adst[t] = a_all[(size_t)n * 16 + 8 + t];
  __syncthreads();
  int hd = t & 7, lj = t >> 3;
  float m = -1e30f;
  for (int j = lj; j < cnt; j += 32) {
    int s = srcs[base + j];
    float v = a_all[(size_t)s * 16 + hd] + adst[hd];
    v = v > 0.f ? v : NEG_SLOPE * v;
    m = fmaxf(m, v);
  }
  red[t] = m;
  __syncthreads();
  #pragma unroll
  for (int off = 128; off >= 8; off >>= 1) {
    if (t < off) red[t] = fmaxf(red[t], red[t + off]);
    __syncthreads();
  }
  if (t < 8) emax[t] = red[t];
  __syncthreads();
  float ssum = 0.f;
  for (int j = lj; j < cnt; j += 32) {
    int s = srcs[base + j];
    float v = a_all[(size_t)s * 16 + hd] + adst[hd];
    v = v > 0.f ? v : NEG_SLOPE * v;
    ssum += expf(v - emax[hd]);
  }
  red[t] = ssum;
  __syncthreads();
  #pragma unroll
  for (int off = 128; off >= 8; off >>= 1) {
    if (t < off) red[t] += red[t + off];
    __syncthreads();
  }
  if (t < 8) esum[t] = red[t] + 1e-16f;
  __syncthreads();
  int d = t & 127, hg = t >> 7;
  float acc[4] = {0.f, 0.f, 0.f, 0.f};
  for (int j0 = 0; j0 < cnt; j0 += 32) {
    int j = j0 + lj;
    if (j < cnt) {
      int s = srcs[base + j];
      if (hd == 0) src_s[lj] = s;
      float v = a_all[(size_t)s * 16 + hd] + adst[hd];
      v = v > 0.f ? v : NEG_SLOPE * v;
      alpha_s[lj][hd] = expf(v - emax[hd]) / esum[hd];
    }
    __syncthreads();
    int lim = cnt - j0; if (lim > 32) lim = 32;
    for (int el = 0; el < lim; ++el) {
      float v = bf2f(xb[(size_t)src_s[el] * INC + d]);
      #pragma unroll
      for (int k = 0; k < 4; ++k) acc[k] += v * alpha_s[el][hg * 4 + k];
    }
    __syncthreads();
  }
  #pragma unroll
  for (int k = 0; k < 4; ++k)
    aggb[(size_t)n * 1024 + (hg * 4 + k) * INC + d] = f2bf(acc[k]);
}

// ---------------- per-head GEMM: x1 = relu(agg_hd @ W_hd + b_gat) ----------------
// 128x256 tile (full head), 512 threads / 8 waves (64x64 each), K=128, dbuf.
__global__ __launch_bounds__(512) void gemm_gat(
    const ushort_t* __restrict__ A, const ushort_t* __restrict__ BT,
    const float* __restrict__ b_gat, ushort_t* __restrict__ x1, int M)
{
  __shared__ ushort_t As[2][128][32];   // 8 KB/buf
  __shared__ ushort_t Bs[2][256][32];   // 16 KB/buf
  int tid = threadIdx.x;
  int wave = tid >> 6, lane = tid & 63;
  int row0 = blockIdx.x * 128;
  int head = blockIdx.y;
  const ushort_t* Abase = A + head * INC;                     // row stride 1024
  const ushort_t* Bbase = BT + (size_t)head * 256 * INC;      // 256 rows, stride 128
  int wr = (wave >> 2) * 64, wc = (wave & 3) * 64;
  int lc = lane & 15, kg = lane >> 4;
  int sc = src_chunk(lane), srow = lane >> 2;

  f32x4 acc[4][4] = {};

  #define STAGE_G(buf, kt)                                                        \
    {                                                                             \
      int ga = row0 + wave * 16 + srow; if (ga >= M) ga = M - 1;                  \
      gload_lds16(Abase + (size_t)ga * 1024 + (kt) + sc * 8, &As[buf][wave * 16][0]); \
      _Pragma("unroll")                                                           \
      for (int c = 0; c < 2; ++c) {                                               \
        int r = c * 128 + wave * 16 + srow;                                       \
        gload_lds16(Bbase + (size_t)r * INC + (kt) + sc * 8, &Bs[buf][c * 128 + wave * 16][0]); \
      }                                                                           \
    }

  #define COMPUTE_G(buf)                                                          \
    {                                                                             \
      bf16x8 af[4], bfr[4];                                                       \
      _Pragma("unroll")                                                           \
      for (int mi = 0; mi < 4; ++mi)                                              \
        af[mi] = *(const bf16x8*)&As[buf][wr + mi * 16 + lc][rd_chunk(lc, kg) * 8]; \
      _Pragma("unroll")                                                           \
      for (int ni = 0; ni < 4; ++ni)                                              \
        bfr[ni] = *(const bf16x8*)&Bs[buf][wc + ni * 16 + lc][rd_chunk(lc, kg) * 8]; \
      _Pragma("unroll")                                                           \
      for (int mi = 0; mi < 4; ++mi)                                              \
        _Pragma("unroll")                                                         \
        for (int ni = 0; ni < 4; ++ni)                                            \
          acc[mi][ni] = __builtin_amdgcn_mfma_f32_16x16x32_bf16(af[mi], bfr[ni], acc[mi][ni], 0, 0, 0); \
    }

  STAGE_G(0, 0);
  __syncthreads();
  int cur = 0;
  for (int kt = 32; kt < INC; kt += 32) {
    STAGE_G(cur ^ 1, kt);
    COMPUTE_G(cur);
    __syncthreads();
    cur ^= 1;
  }
  COMPUTE_G(cur);
  #undef STAGE_G
  #undef COMPUTE_G

  int gcol0 = head * 256;
  float bg[4];
  #pragma unroll
  for (int ni = 0; ni < 4; ++ni) bg[ni] = b_gat[gcol0 + wc + ni * 16 + lc];
  #pragma unroll
  for (int mi = 0; mi < 4; ++mi) {
    #pragma unroll
    for (int r = 0; r < 4; ++r) {
      int grow = row0 + wr + mi * 16 + kg * 4 + r;
      if (grow < M) {
        #pragma unroll
        for (int ni = 0; ni < 4; ++ni) {
          float v = acc[mi][ni][r] + bg[ni];
          x1[(size_t)grow * GDIM + gcol0 + wc + ni * 16 + lc] = f2bf(v > 0.f ? v : 0.f);
        }
      }
    }
  }
}

// ---------------- SAGE GEMM split-K: ypart[z] = bf16(A[:,kz] * BT[:,kz]^T) ----------------
// 128x256 tile, 512 threads / 8 waves (64x64 each), dbuf, KSPLIT=2.
__global__ __launch_bounds__(512) void gemm_sage(
    const ushort_t* __restrict__ A, const ushort_t* __restrict__ BT,
    ushort_t* __restrict__ Cp, int M, int Nc, int K, int Klen)
{
  __shared__ ushort_t As[2][128][32];   // 8 KB/buf
  __shared__ ushort_t Bs[2][256][32];   // 16 KB/buf
  int tid = threadIdx.x;
  int wave = tid >> 6, lane = tid & 63;
  int row0 = blockIdx.x * 128, col0 = blockIdx.y * 256;
  int k0 = blockIdx.z * Klen;
  ushort_t* C = Cp + (size_t)blockIdx.z * M * Nc;
  int wr = (wave >> 2) * 64, wc = (wave & 3) * 64;
  int lc = lane & 15, kg = lane >> 4;
  int sc = src_chunk(lane), srow = lane >> 2;

  f32x4 acc[4][4] = {};

  #define STAGE_S(buf, kt)                                                        \
    {                                                                             \
      int ga = row0 + wave * 16 + srow; if (ga >= M) ga = M - 1;                  \
      gload_lds16(A + (size_t)ga * K + (kt) + sc * 8, &As[buf][wave * 16][0]);    \
      _Pragma("unroll")                                                           \
      for (int c = 0; c < 2; ++c) {                                               \
        int gb = col0 + c * 128 + wave * 16 + srow;                               \
        gload_lds16(BT + (size_t)gb * K + (kt) + sc * 8, &Bs[buf][c * 128 + wave * 16][0]); \
      }                                                                           \
    }

  #define COMPUTE_S(buf)                                                          \
    {                                                                             \
      bf16x8 af[4], bfr[4];                                                       \
      _Pragma("unroll")                                                           \
      for (int mi = 0; mi < 4; ++mi)                                              \
        af[mi] = *(const bf16x8*)&As[buf][wr + mi * 16 + lc][rd_chunk(lc, kg) * 8]; \
      _Pragma("unroll")                                                           \
      for (int ni = 0; ni < 4; ++ni)                                              \
        bfr[ni] = *(const bf16x8*)&Bs[buf][wc + ni * 16 + lc][rd_chunk(lc, kg) * 8]; \
      _Pragma("unroll")                                                           \
      for (int mi = 0; mi < 4; ++mi)                                              \
        _Pragma("unroll")                                                         \
        for (int ni = 0; ni < 4; ++ni)                                            \
          acc[mi][ni] = __builtin_amdgcn_mfma_f32_16x16x32_bf16(af[mi], bfr[ni], acc[mi][ni], 0, 0, 0); \
    }

  STAGE_S(0, k0);
  __syncthreads();
  int cur = 0;
  for (int kt = k0 + 32; kt < k0 + Klen; kt += 32) {
    STAGE_S(cur ^ 1, kt);
    COMPUTE_S(cur);
    __syncthreads();
    cur ^= 1;
  }
  COMPUTE_S(cur);
  #undef STAGE_S
  #undef COMPUTE_S

  #pragma unroll
  for (int mi = 0; mi < 4; ++mi) {
    #pragma unroll
    for (int r = 0; r < 4; ++r) {
      int grow = row0 + wr + mi * 16 + kg * 4 + r;
      if (grow < M) {
        #pragma unroll
        for (int ni = 0; ni < 4; ++ni)
          C[(size_t)grow * Nc + col0 + wc + ni * 16 + lc] = f2bf(acc[mi][ni][r]);
      }
    }
  }
}

// ---------------- yb = bf16(sum of KSPLIT bf16 partials) ----------------
__global__ __launch_bounds__(256) void yreduce(
    const ushort_t* __restrict__ yp, ushort_t* __restrict__ yb, size_t stride, int total8)
{
  int i = blockIdx.x * 256 + threadIdx.x;
  if (i >= total8) return;
  size_t off = (size_t)i * 8;
  float s[8] = {0.f, 0.f, 0.f, 0.f, 0.f, 0.f, 0.f, 0.f};
  #pragma unroll
  for (int z = 0; z < KSPLIT; ++z) {
    u16x8 v = *(const u16x8*)(yp + z * stride + off);
    #pragma unroll
    for (int k = 0; k < 8; ++k) s[k] += bf2f(v[k]);
  }
  u16x8 o;
  #pragma unroll
  for (int k = 0; k < 8; ++k) o[k] = f2bf(s[k]);
  *(u16x8*)(yb + off) = o;
}

// ---------------- fused SAGE aggregate + MLP head, 16 nodes / 512 threads ----------------
__global__ __launch_bounds__(512) void sage_mlp(
    const ushort_t* __restrict__ yb, const int* __restrict__ start, const int* __restrict__ deg,
    const int* __restrict__ srcs, const float* __restrict__ b_l,
    const float* __restrict__ W1, const float* __restrict__ b1,
    const float* __restrict__ W2, const float* __restrict__ b2, float* __restrict__ out, int N)
{
  __shared__ float xs[16][256];   // 16 KB
  __shared__ float wred[8][4];
  int t = threadIdx.x;
  int wv = t >> 6, lane = t & 63;
  int b0 = blockIdx.x * 16;

  int half = lane >> 5;        // 0: edge j, 1: edge j+1
  int col32 = lane & 31;       // covers cols col32*8 .. +8
  #pragma unroll
  for (int i = 0; i < 2; ++i) {
    int nl = wv * 2 + i;
    int n = b0 + nl;
    float acc[8] = {0.f, 0.f, 0.f, 0.f, 0.f, 0.f, 0.f, 0.f};
    if (n < N) {
      int cnt = deg[n];
      int base = start[n];
      for (int j = 0; j < cnt; j += 2) {
        int jj = j + half;
        if (jj < cnt) {
          int s = srcs[base + jj];
          u16x8 v = *(const u16x8*)(yb + (size_t)s * 512 + col32 * 8);
          #pragma unroll
          for (int k = 0; k < 8; ++k) acc[k] += bf2f(v[k]);
        }
      }
      #pragma unroll
      for (int k = 0; k < 8; ++k) acc[k] += __shfl_xor(acc[k], 32);
      if (half == 0) {
        float d = (float)cnt; if (d < 1.f) d = 1.f;
        u16x8 r = *(const u16x8*)(yb + (size_t)n * 512 + 256 + col32 * 8);
        #pragma unroll
        for (int k = 0; k < 8; ++k) {
          float v = acc[k] / d + bf2f(r[k]) + b_l[col32 * 8 + k];
          xs[nl][col32 * 8 + k] = v > 0.f ? v : 0.f;
        }
      }
    } else if (half == 0) {
      #pragma unroll
      for (int k = 0; k < 8; ++k) xs[nl][col32 * 8 + k] = 0.f;
    }
  }
  __syncthreads();

  int c = t & 127, g = t >> 7;  // g in 0..3 -> nodes g*4..g*4+3
  float acc[4];
  float bb = b1[c];
  #pragma unroll
  for (int nn = 0; nn < 4; ++nn) acc[nn] = bb;
  for (int k = 0; k < 256; ++k) {
    float w = W1[k * 128 + c];
    #pragma unroll
    for (int nn = 0; nn < 4; ++nn) acc[nn] += xs[g * 4 + nn][k] * w;
  }
  float w2 = W2[c];
  float p[4];
  #pragma unroll
  for (int nn = 0; nn < 4; ++nn) {
    float hm = acc[nn] > 0.f ? acc[nn] : 0.f;
    p[nn] = hm * w2;
  }
  #pragma unroll
  for (int off = 32; off >= 1; off >>= 1)
    #pragma unroll
    for (int nn = 0; nn < 4; ++nn) p[nn] += __shfl_down(p[nn], off);
  if (lane == 0) {
    #pragma unroll
    for (int nn = 0; nn < 4; ++nn) wred[wv][nn] = p[nn];
  }
  __syncthreads();
  if (t < 16) {
    int gg = t >> 2, nn = t & 3;
    int node = b0 + gg * 4 + nn;
    if (node < N)
      out[node] = wred[gg * 2][nn] + wred[gg * 2 + 1][nn] + b2[0];
  }
}

extern "C" void kernel_launch(void* const* d_in, const int* in_sizes, int n_in,
                              void* d_out, int out_size, void* d_ws, size_t ws_size,
                              hipStream_t stream)
{
  const float* x        = (const float*)d_in[0];
  const int*   ei       = (const int*)d_in[1];
  const float* W_gat    = (const float*)d_in[3];
  const float* att_src  = (const float*)d_in[4];
  const float* att_dst  = (const float*)d_in[5];
  const float* b_gat    = (const float*)d_in[6];
  const float* W_sage_l = (const float*)d_in[7];
  const float* b_sage_l = (const float*)d_in[8];
  const float* W_sage_r = (const float*)d_in[9];
  const float* W_lin1   = (const float*)d_in[10];
  const float* b_lin1   = (const float*)d_in[11];
  const float* W_lin2   = (const float*)d_in[12];
  const float* b_lin2   = (const float*)d_in[13];
  float* out = (float*)d_out;

  const int N = in_sizes[0] / INC;   // 10000
  const int E = in_sizes[1] / 2;     // 80000

  // ---- workspace carve ----
  char* p = (char*)d_ws;
  ushort_t* x1b   = (ushort_t*)p;         p += (size_t)N * GDIM * 2;
  ushort_t* aggb  = (ushort_t*)p;         p += (size_t)N * 1024 * 2;
  ushort_t* ypart = (ushort_t*)p;         p += (size_t)KSPLIT * N * 512 * 2;
  ushort_t* yb    = (ushort_t*)p;         p += (size_t)N * 512 * 2;
  ushort_t* xb    = (ushort_t*)p;         p += (size_t)N * INC * 2;
  ushort_t* WgatT = (ushort_t*)p;         p += (size_t)GDIM * INC * 2;
  ushort_t* WsT   = (ushort_t*)p;         p += (size_t)512 * GDIM * 2;
  float*    wt    = (float*)p;            p += (size_t)16 * 128 * 4;
  float*    a_all = (float*)p;            p += (size_t)N * 16 * 4;
  int*      deg   = (int*)p;              p += (size_t)N * 4;
  int*      start = (int*)p;              p += (size_t)N * 4;
  int*      cursor= (int*)p;              p += (size_t)N * 4;
  int*      srcs  = (int*)p;              p += (size_t)E * 4;

  // 0a) zero deg with a proper kernel (runtime blit for 40 KB is ~42 us in-graph)
  zero_deg<<<(N + 255) / 256, 256, 0, stream>>>(deg, N);

  // 0b) fused prep (x convert, transposes, deg_count, wtilde)
  int nbX   = (N * INC + 1023) / 1024;
  int nbWg  = (INC / 32) * (GDIM / 32);
  int nbWs  = (GDIM / 32) * (HID / 32);
  int nbDeg = (E + 255) / 256;
  int o1 = nbX, o2 = o1 + nbWg, o3 = o2 + nbWs, o4 = o3 + nbWs, o5 = o4 + nbDeg;
  int nbTot = o5 + 16;
  prep<<<nbTot, 256, 0, stream>>>(x, xb, W_gat, WgatT, W_sage_l, W_sage_r, WsT,
                                  ei, deg, E, att_src, att_dst, wt, o1, o2, o3, o4, o5);

  // CSR finish
  scan_deg<<<1, 1024, 0, stream>>>(deg, start, cursor, N);
  fill_buckets<<<(E + 255) / 256, 256, 0, stream>>>(ei, cursor, srcs, E);

  // 1) attention logits a_all[n][16]
  a_dots<<<(N + 15) / 16, 256, 0, stream>>>(xb, wt, a_all, N);

  // 2) GAT softmax + x-space aggregate -> aggb
  gat_aggregate<<<N, 256, 0, stream>>>(xb, a_all, start, deg, srcs, aggb, N);

  // 3) per-head GEMM (128x256, 8 waves): x1 = relu(agg @ W_hd + b_gat)
  { dim3 grid((N + 127) / 128, HEADS);
    gemm_gat<<<grid, 512, 0, stream>>>(aggb, WgatT, b_gat, x1b, N); }

  // 4) split-K SAGE GEMM (128x256, 8 waves) -> 2 bf16 partials, then reduce
  { dim3 grid((N + 127) / 128, 512 / 256, KSPLIT);
    gemm_sage<<<grid, 512, 0, stream>>>(x1b, WsT, ypart, N, 512, GDIM, GDIM / KSPLIT); }
  { int total8 = N * 512 / 8;
    yreduce<<<(total8 + 255) / 256, 256, 0, stream>>>(ypart, yb, (size_t)N * 512, total8); }

  // 5) fused SAGE mean-aggregate + MLP head -> out
  sage_mlp<<<(N + 15) / 16, 512, 0, stream>>>(yb, start, deg, srcs, b_sage_l,
                                              W_lin1, b_lin1, W_lin2, b_lin2, out, N);
}

// Round 16
// 162.242 us; speedup vs baseline: 1.0283x; 1.0283x over previous
//
#include <hip/hip_runtime.h>
#include <math.h>

#define HEADS 8
#define HID 256
#define INC 128
#define GDIM 2048  // HEADS*HID
#define NEG_SLOPE 0.2f
#define KSPLIT 2

typedef unsigned short ushort_t;
typedef short bf16x8 __attribute__((ext_vector_type(8)));
typedef ushort_t u16x8 __attribute__((ext_vector_type(8)));
typedef float f32x4 __attribute__((ext_vector_type(4)));

__device__ __forceinline__ ushort_t f2bf(float f) {
  union { float f; unsigned u; } v; v.f = f;
  unsigned r = (v.u + 0x7FFF + ((v.u >> 16) & 1)) >> 16;  // RTNE
  return (ushort_t)r;
}
__device__ __forceinline__ float bf2f(ushort_t u) {
  union { unsigned u; float f; } v; v.u = ((unsigned)u) << 16;
  return v.f;
}

__device__ __forceinline__ void gload_lds16(const ushort_t* g, ushort_t* l) {
  __builtin_amdgcn_global_load_lds(
      (const __attribute__((address_space(1))) unsigned int*)g,
      (__attribute__((address_space(3))) unsigned int*)l, 16, 0, 0);
}

// LDS chunk swizzle (verified r4/r5: SQ_LDS_BANK_CONFLICT -> 0)
__device__ __forceinline__ int src_chunk(int lane) {
  return ((lane & 3) - ((lane >> 3) & 3)) & 3;
}
__device__ __forceinline__ int rd_chunk(int lc, int kg) {
  return (kg + ((lc >> 1) & 3)) & 3;
}

// ---------------- custom zero ----------------
__global__ __launch_bounds__(256) void zero_deg(int* __restrict__ deg, int n)
{
  int i = blockIdx.x * 256 + threadIdx.x;
  if (i < n) deg[i] = 0;
}

// ---------------- fused prep: x->bf16, 3 weight transposes, deg_count, wtilde ----------------
__global__ __launch_bounds__(256) void prep(
    const float* __restrict__ x, ushort_t* __restrict__ xb,
    const float* __restrict__ Wg, ushort_t* __restrict__ WgT,
    const float* __restrict__ Wl, const float* __restrict__ Wr, ushort_t* __restrict__ WsT,
    const int* __restrict__ ei, int* __restrict__ deg, int E,
    const float* __restrict__ att_s, const float* __restrict__ att_d, float* __restrict__ wt,
    int o1, int o2, int o3, int o4, int o5)
{
  __shared__ float tile[32][33];
  __shared__ float attl[256];
  int b = blockIdx.x, t = threadIdx.x;
  if (b < o1) {
    int i = b * 1024 + t * 4;
    float4 v = *(const float4*)(x + i);
    ushort_t o[4] = {f2bf(v.x), f2bf(v.y), f2bf(v.z), f2bf(v.w)};
    *(unsigned long long*)(xb + i) = *(unsigned long long*)o;
  } else if (b < o4) {
    const float* src; ushort_t* dst; int R, C, rowOff, bx, by;
    if (b < o2)      { int idx = b - o1; src = Wg; dst = WgT; R = INC;  C = GDIM; rowOff = 0;   bx = idx % (INC / 32);  by = idx / (INC / 32); }
    else if (b < o3) { int idx = b - o2; src = Wl; dst = WsT; R = GDIM; C = HID;  rowOff = 0;   bx = idx % (GDIM / 32); by = idx / (GDIM / 32); }
    else             { int idx = b - o3; src = Wr; dst = WsT; R = GDIM; C = HID;  rowOff = HID; bx = idx % (GDIM / 32); by = idx / (GDIM / 32); }
    int tx = t & 31, ty = t >> 5;
    int r0 = bx * 32, c0 = by * 32;
    #pragma unroll
    for (int i = 0; i < 32; i += 8)
      tile[ty + i][tx] = src[(size_t)(r0 + ty + i) * C + c0 + tx];
    __syncthreads();
    #pragma unroll
    for (int i = 0; i < 32; i += 8)
      dst[(size_t)(rowOff + c0 + ty + i) * R + r0 + tx] = f2bf(tile[tx][ty + i]);
  } else if (b < o5) {
    int e = (b - o4) * 256 + t;
    if (e < E) atomicAdd(&deg[ei[E + e]], 1);
  } else {
    int j = b - o5;                 // 0..15
    int hd = j & 7;
    const float* att = (j < 8) ? att_s : att_d;
    if (t < 256) attl[t] = att[hd * 256 + t];
    __syncthreads();
    if (t < 128) {
      float acc = 0.f;
      #pragma unroll 8
      for (int c = 0; c < 256; ++c)
        acc += Wg[(size_t)t * GDIM + hd * 256 + c] * attl[c];
      wt[j * 128 + t] = acc;
    }
  }
}

// ---------------- CSR scan over deg[N] (40 KB), 1024 threads ----------------
__global__ __launch_bounds__(1024) void scan_deg(const int* __restrict__ deg, int* __restrict__ start,
                                                 int* __restrict__ cursor, int N)
{
  __shared__ int sums[1024];
  int t = threadIdx.x;
  int chunk = (N + 1023) / 1024;
  int s = 0;
  for (int i = 0; i < chunk; ++i) {
    int idx = t * chunk + i;
    if (idx < N) s += deg[idx];
  }
  sums[t] = s;
  __syncthreads();
  for (int off = 1; off < 1024; off <<= 1) {
    int v = (t >= off) ? sums[t - off] : 0;
    __syncthreads();
    sums[t] += v;
    __syncthreads();
  }
  int run = (t == 0) ? 0 : sums[t - 1];
  for (int i = 0; i < chunk; ++i) {
    int idx = t * chunk + i;
    if (idx < N) { start[idx] = run; cursor[idx] = run; run += deg[idx]; }
  }
}

// ---------------- fused: fill CSR buckets + attention logits ----------------
// blocks [0, nbFill): fill srcs; blocks [nbFill, ...): a_all[n][16] dots
__global__ __launch_bounds__(256) void fill_adots(
    const int* __restrict__ ei, int* __restrict__ cursor, int* __restrict__ srcs, int E, int nbFill,
    const ushort_t* __restrict__ xb, const float* __restrict__ wt,
    float* __restrict__ a_all, int N)
{
  int t = threadIdx.x;
  if (blockIdx.x < nbFill) {
    int e = blockIdx.x * 256 + t;
    if (e < E) {
      int n = ei[E + e];
      int p = atomicAdd(&cursor[n], 1);
      srcs[p] = ei[e];
    }
    return;
  }
  __shared__ float wts[16][132];
  __shared__ ushort_t xs[16 * 128];
  for (int i = t; i < 2048; i += 256) wts[i >> 7][i & 127] = wt[i];
  int b0 = (blockIdx.x - nbFill) * 16;
  {
    int row = t >> 4, off = (t & 15) * 8;
    int n = b0 + row; if (n >= N) n = N - 1;
    *(u16x8*)&xs[row * 128 + off] = *(const u16x8*)(xb + (size_t)n * 128 + off);
  }
  __syncthreads();
  int nl = t >> 4, j = t & 15;
  float acc = 0.f;
  #pragma unroll 8
  for (int k = 0; k < 128; ++k)
    acc += bf2f(xs[nl * 128 + k]) * wts[j][k];
  int n = b0 + nl;
  if (n < N) a_all[(size_t)n * 16 + j] = acc;
}

// ---------------- GAT softmax + x-space aggregate -> aggb[N][8][128] bf16 ----------------
__global__ __launch_bounds__(256) void gat_aggregate(
    const ushort_t* __restrict__ xb, const float* __restrict__ a_all,
    const int* __restrict__ start, const int* __restrict__ deg,
    const int* __restrict__ srcs, ushort_t* __restrict__ aggb, int N)
{
  int n = blockIdx.x, t = threadIdx.x;
  __shared__ float adst[8];
  __shared__ float emax[8];
  __shared__ float esum[8];
  __shared__ float red[256];
  __shared__ float alpha_s[32][8];
  __shared__ int src_s[32];
  int cnt = deg[n];
  int base = start[n];
  if (t < 8) adst[t] = a_all[(size_t)n * 16 + 8 + t];
  __syncthreads();
  int hd = t & 7, lj = t >> 3;
  float m = -1e30f;
  for (int j = lj; j < cnt; j += 32) {
    int s = srcs[base + j];
    float v = a_all[(size_t)s * 16 + hd] + adst[hd];
    v = v > 0.f ? v : NEG_SLOPE * v;
    m = fmaxf(m, v);
  }
  red[t] = m;
  __syncthreads();
  #pragma unroll
  for (int off = 128; off >= 8; off >>= 1) {
    if (t < off) red[t] = fmaxf(red[t], red[t + off]);
    __syncthreads();
  }
  if (t < 8) emax[t] = red[t];
  __syncthreads();
  float ssum = 0.f;
  for (int j = lj; j < cnt; j += 32) {
    int s = srcs[base + j];
    float v = a_all[(size_t)s * 16 + hd] + adst[hd];
    v = v > 0.f ? v : NEG_SLOPE * v;
    ssum += expf(v - emax[hd]);
  }
  red[t] = ssum;
  __syncthreads();
  #pragma unroll
  for (int off = 128; off >= 8; off >>= 1) {
    if (t < off) red[t] += red[t + off];
    __syncthreads();
  }
  if (t < 8) esum[t] = red[t] + 1e-16f;
  __syncthreads();
  int d = t & 127, hg = t >> 7;
  float acc[4] = {0.f, 0.f, 0.f, 0.f};
  for (int j0 = 0; j0 < cnt; j0 += 32) {
    int j = j0 + lj;
    if (j < cnt) {
      int s = srcs[base + j];
      if (hd == 0) src_s[lj] = s;
      float v = a_all[(size_t)s * 16 + hd] + adst[hd];
      v = v > 0.f ? v : NEG_SLOPE * v;
      alpha_s[lj][hd] = expf(v - emax[hd]) / esum[hd];
    }
    __syncthreads();
    int lim = cnt - j0; if (lim > 32) lim = 32;
    for (int el = 0; el < lim; ++el) {
      float v = bf2f(xb[(size_t)src_s[el] * INC + d]);
      #pragma unroll
      for (int k = 0; k < 4; ++k) acc[k] += v * alpha_s[el][hg * 4 + k];
    }
    __syncthreads();
  }
  #pragma unroll
  for (int k = 0; k < 4; ++k)
    aggb[(size_t)n * 1024 + (hg * 4 + k) * INC + d] = f2bf(acc[k]);
}

// ---------------- per-head GEMM: x1 = relu(agg_hd @ W_hd + b_gat) ----------------
// 128x256 tile (full head), 512 threads / 8 waves (64x64 each), K=128, dbuf.
__global__ __launch_bounds__(512) void gemm_gat(
    const ushort_t* __restrict__ A, const ushort_t* __restrict__ BT,
    const float* __restrict__ b_gat, ushort_t* __restrict__ x1, int M)
{
  __shared__ ushort_t As[2][128][32];   // 8 KB/buf
  __shared__ ushort_t Bs[2][256][32];   // 16 KB/buf
  int tid = threadIdx.x;
  int wave = tid >> 6, lane = tid & 63;
  int row0 = blockIdx.x * 128;
  int head = blockIdx.y;
  const ushort_t* Abase = A + head * INC;                     // row stride 1024
  const ushort_t* Bbase = BT + (size_t)head * 256 * INC;      // 256 rows, stride 128
  int wr = (wave >> 2) * 64, wc = (wave & 3) * 64;
  int lc = lane & 15, kg = lane >> 4;
  int sc = src_chunk(lane), srow = lane >> 2;

  f32x4 acc[4][4] = {};

  #define STAGE_G(buf, kt)                                                        \
    {                                                                             \
      int ga = row0 + wave * 16 + srow; if (ga >= M) ga = M - 1;                  \
      gload_lds16(Abase + (size_t)ga * 1024 + (kt) + sc * 8, &As[buf][wave * 16][0]); \
      _Pragma("unroll")                                                           \
      for (int c = 0; c < 2; ++c) {                                               \
        int r = c * 128 + wave * 16 + srow;                                       \
        gload_lds16(Bbase + (size_t)r * INC + (kt) + sc * 8, &Bs[buf][c * 128 + wave * 16][0]); \
      }                                                                           \
    }

  #define COMPUTE_G(buf)                                                          \
    {                                                                             \
      bf16x8 af[4], bfr[4];                                                       \
      _Pragma("unroll")                                                           \
      for (int mi = 0; mi < 4; ++mi)                                              \
        af[mi] = *(const bf16x8*)&As[buf][wr + mi * 16 + lc][rd_chunk(lc, kg) * 8]; \
      _Pragma("unroll")                                                           \
      for (int ni = 0; ni < 4; ++ni)                                              \
        bfr[ni] = *(const bf16x8*)&Bs[buf][wc + ni * 16 + lc][rd_chunk(lc, kg) * 8]; \
      _Pragma("unroll")                                                           \
      for (int mi = 0; mi < 4; ++mi)                                              \
        _Pragma("unroll")                                                         \
        for (int ni = 0; ni < 4; ++ni)                                            \
          acc[mi][ni] = __builtin_amdgcn_mfma_f32_16x16x32_bf16(af[mi], bfr[ni], acc[mi][ni], 0, 0, 0); \
    }

  STAGE_G(0, 0);
  __syncthreads();
  int cur = 0;
  for (int kt = 32; kt < INC; kt += 32) {
    STAGE_G(cur ^ 1, kt);
    COMPUTE_G(cur);
    __syncthreads();
    cur ^= 1;
  }
  COMPUTE_G(cur);
  #undef STAGE_G
  #undef COMPUTE_G

  int gcol0 = head * 256;
  float bg[4];
  #pragma unroll
  for (int ni = 0; ni < 4; ++ni) bg[ni] = b_gat[gcol0 + wc + ni * 16 + lc];
  #pragma unroll
  for (int mi = 0; mi < 4; ++mi) {
    #pragma unroll
    for (int r = 0; r < 4; ++r) {
      int grow = row0 + wr + mi * 16 + kg * 4 + r;
      if (grow < M) {
        #pragma unroll
        for (int ni = 0; ni < 4; ++ni) {
          float v = acc[mi][ni][r] + bg[ni];
          x1[(size_t)grow * GDIM + gcol0 + wc + ni * 16 + lc] = f2bf(v > 0.f ? v : 0.f);
        }
      }
    }
  }
}

// ---------------- SAGE GEMM split-K: ypart[z] = bf16(A[:,kz] * BT[:,kz]^T) ----------------
// 128x256 tile, 512 threads / 8 waves (64x64 each), dbuf, KSPLIT=2.
__global__ __launch_bounds__(512) void gemm_sage(
    const ushort_t* __restrict__ A, const ushort_t* __restrict__ BT,
    ushort_t* __restrict__ Cp, int M, int Nc, int K, int Klen)
{
  __shared__ ushort_t As[2][128][32];   // 8 KB/buf
  __shared__ ushort_t Bs[2][256][32];   // 16 KB/buf
  int tid = threadIdx.x;
  int wave = tid >> 6, lane = tid & 63;
  int row0 = blockIdx.x * 128, col0 = blockIdx.y * 256;
  int k0 = blockIdx.z * Klen;
  ushort_t* C = Cp + (size_t)blockIdx.z * M * Nc;
  int wr = (wave >> 2) * 64, wc = (wave & 3) * 64;
  int lc = lane & 15, kg = lane >> 4;
  int sc = src_chunk(lane), srow = lane >> 2;

  f32x4 acc[4][4] = {};

  #define STAGE_S(buf, kt)                                                        \
    {                                                                             \
      int ga = row0 + wave * 16 + srow; if (ga >= M) ga = M - 1;                  \
      gload_lds16(A + (size_t)ga * K + (kt) + sc * 8, &As[buf][wave * 16][0]);    \
      _Pragma("unroll")                                                           \
      for (int c = 0; c < 2; ++c) {                                               \
        int gb = col0 + c * 128 + wave * 16 + srow;                               \
        gload_lds16(BT + (size_t)gb * K + (kt) + sc * 8, &Bs[buf][c * 128 + wave * 16][0]); \
      }                                                                           \
    }

  #define COMPUTE_S(buf)                                                          \
    {                                                                             \
      bf16x8 af[4], bfr[4];                                                       \
      _Pragma("unroll")                                                           \
      for (int mi = 0; mi < 4; ++mi)                                              \
        af[mi] = *(const bf16x8*)&As[buf][wr + mi * 16 + lc][rd_chunk(lc, kg) * 8]; \
      _Pragma("unroll")                                                           \
      for (int ni = 0; ni < 4; ++ni)                                              \
        bfr[ni] = *(const bf16x8*)&Bs[buf][wc + ni * 16 + lc][rd_chunk(lc, kg) * 8]; \
      _Pragma("unroll")                                                           \
      for (int mi = 0; mi < 4; ++mi)                                              \
        _Pragma("unroll")                                                         \
        for (int ni = 0; ni < 4; ++ni)                                            \
          acc[mi][ni] = __builtin_amdgcn_mfma_f32_16x16x32_bf16(af[mi], bfr[ni], acc[mi][ni], 0, 0, 0); \
    }

  STAGE_S(0, k0);
  __syncthreads();
  int cur = 0;
  for (int kt = k0 + 32; kt < k0 + Klen; kt += 32) {
    STAGE_S(cur ^ 1, kt);
    COMPUTE_S(cur);
    __syncthreads();
    cur ^= 1;
  }
  COMPUTE_S(cur);
  #undef STAGE_S
  #undef COMPUTE_S

  #pragma unroll
  for (int mi = 0; mi < 4; ++mi) {
    #pragma unroll
    for (int r = 0; r < 4; ++r) {
      int grow = row0 + wr + mi * 16 + kg * 4 + r;
      if (grow < M) {
        #pragma unroll
        for (int ni = 0; ni < 4; ++ni)
          C[(size_t)grow * Nc + col0 + wc + ni * 16 + lc] = f2bf(acc[mi][ni][r]);
      }
    }
  }
}

// ---------------- fused SAGE aggregate + MLP head, 16 nodes / 512 threads ----------------
// Gathers directly from BOTH ypart halves (no yreduce); partial sums combined in fp32.
__global__ __launch_bounds__(512) void sage_mlp(
    const ushort_t* __restrict__ yp, size_t ypstride,
    const int* __restrict__ start, const int* __restrict__ deg,
    const int* __restrict__ srcs, const float* __restrict__ b_l,
    const float* __restrict__ W1, const float* __restrict__ b1,
    const float* __restrict__ W2, const float* __restrict__ b2, float* __restrict__ out, int N)
{
  __shared__ float xs[16][256];   // 16 KB
  __shared__ float wred[8][4];
  const ushort_t* yp0 = yp;
  const ushort_t* yp1 = yp + ypstride;
  int t = threadIdx.x;
  int wv = t >> 6, lane = t & 63;
  int b0 = blockIdx.x * 16;

  int half = lane >> 5;        // 0: edge j, 1: edge j+1
  int col32 = lane & 31;       // covers cols col32*8 .. +8
  #pragma unroll
  for (int i = 0; i < 2; ++i) {
    int nl = wv * 2 + i;
    int n = b0 + nl;
    float acc[8] = {0.f, 0.f, 0.f, 0.f, 0.f, 0.f, 0.f, 0.f};
    if (n < N) {
      int cnt = deg[n];
      int base = start[n];
      for (int j = 0; j < cnt; j += 2) {
        int jj = j + half;
        if (jj < cnt) {
          int s = srcs[base + jj];
          u16x8 v0 = *(const u16x8*)(yp0 + (size_t)s * 512 + col32 * 8);
          u16x8 v1 = *(const u16x8*)(yp1 + (size_t)s * 512 + col32 * 8);
          #pragma unroll
          for (int k = 0; k < 8; ++k) acc[k] += bf2f(v0[k]) + bf2f(v1[k]);
        }
      }
      #pragma unroll
      for (int k = 0; k < 8; ++k) acc[k] += __shfl_xor(acc[k], 32);
      if (half == 0) {
        float d = (float)cnt; if (d < 1.f) d = 1.f;
        u16x8 r0 = *(const u16x8*)(yp0 + (size_t)n * 512 + 256 + col32 * 8);
        u16x8 r1 = *(const u16x8*)(yp1 + (size_t)n * 512 + 256 + col32 * 8);
        #pragma unroll
        for (int k = 0; k < 8; ++k) {
          float v = acc[k] / d + bf2f(r0[k]) + bf2f(r1[k]) + b_l[col32 * 8 + k];
          xs[nl][col32 * 8 + k] = v > 0.f ? v : 0.f;
        }
      }
    } else if (half == 0) {
      #pragma unroll
      for (int k = 0; k < 8; ++k) xs[nl][col32 * 8 + k] = 0.f;
    }
  }
  __syncthreads();

  int c = t & 127, g = t >> 7;  // g in 0..3 -> nodes g*4..g*4+3
  float acc[4];
  float bb = b1[c];
  #pragma unroll
  for (int nn = 0; nn < 4; ++nn) acc[nn] = bb;
  for (int k = 0; k < 256; ++k) {
    float w = W1[k * 128 + c];
    #pragma unroll
    for (int nn = 0; nn < 4; ++nn) acc[nn] += xs[g * 4 + nn][k] * w;
  }
  float w2 = W2[c];
  float p[4];
  #pragma unroll
  for (int nn = 0; nn < 4; ++nn) {
    float hm = acc[nn] > 0.f ? acc[nn] : 0.f;
    p[nn] = hm * w2;
  }
  #pragma unroll
  for (int off = 32; off >= 1; off >>= 1)
    #pragma unroll
    for (int nn = 0; nn < 4; ++nn) p[nn] += __shfl_down(p[nn], off);
  if (lane == 0) {
    #pragma unroll
    for (int nn = 0; nn < 4; ++nn) wred[wv][nn] = p[nn];
  }
  __syncthreads();
  if (t < 16) {
    int gg = t >> 2, nn = t & 3;
    int node = b0 + gg * 4 + nn;
    if (node < N)
      out[node] = wred[gg * 2][nn] + wred[gg * 2 + 1][nn] + b2[0];
  }
}

extern "C" void kernel_launch(void* const* d_in, const int* in_sizes, int n_in,
                              void* d_out, int out_size, void* d_ws, size_t ws_size,
                              hipStream_t stream)
{
  const float* x        = (const float*)d_in[0];
  const int*   ei       = (const int*)d_in[1];
  const float* W_gat    = (const float*)d_in[3];
  const float* att_src  = (const float*)d_in[4];
  const float* att_dst  = (const float*)d_in[5];
  const float* b_gat    = (const float*)d_in[6];
  const float* W_sage_l = (const float*)d_in[7];
  const float* b_sage_l = (const float*)d_in[8];
  const float* W_sage_r = (const float*)d_in[9];
  const float* W_lin1   = (const float*)d_in[10];
  const float* b_lin1   = (const float*)d_in[11];
  const float* W_lin2   = (const float*)d_in[12];
  const float* b_lin2   = (const float*)d_in[13];
  float* out = (float*)d_out;

  const int N = in_sizes[0] / INC;   // 10000
  const int E = in_sizes[1] / 2;     // 80000

  // ---- workspace carve ----
  char* p = (char*)d_ws;
  ushort_t* x1b   = (ushort_t*)p;         p += (size_t)N * GDIM * 2;
  ushort_t* aggb  = (ushort_t*)p;         p += (size_t)N * 1024 * 2;
  ushort_t* ypart = (ushort_t*)p;         p += (size_t)KSPLIT * N * 512 * 2;
  ushort_t* xb    = (ushort_t*)p;         p += (size_t)N * INC * 2;
  ushort_t* WgatT = (ushort_t*)p;         p += (size_t)GDIM * INC * 2;
  ushort_t* WsT   = (ushort_t*)p;         p += (size_t)512 * GDIM * 2;
  float*    wt    = (float*)p;            p += (size_t)16 * 128 * 4;
  float*    a_all = (float*)p;            p += (size_t)N * 16 * 4;
  int*      deg   = (int*)p;              p += (size_t)N * 4;
  int*      start = (int*)p;              p += (size_t)N * 4;
  int*      cursor= (int*)p;              p += (size_t)N * 4;
  int*      srcs  = (int*)p;              p += (size_t)E * 4;

  // 0a) zero deg
  zero_deg<<<(N + 255) / 256, 256, 0, stream>>>(deg, N);

  // 0b) fused prep (x convert, transposes, deg_count, wtilde)
  int nbX   = (N * INC + 1023) / 1024;
  int nbWg  = (INC / 32) * (GDIM / 32);
  int nbWs  = (GDIM / 32) * (HID / 32);
  int nbDeg = (E + 255) / 256;
  int o1 = nbX, o2 = o1 + nbWg, o3 = o2 + nbWs, o4 = o3 + nbWs, o5 = o4 + nbDeg;
  int nbTot = o5 + 16;
  prep<<<nbTot, 256, 0, stream>>>(x, xb, W_gat, WgatT, W_sage_l, W_sage_r, WsT,
                                  ei, deg, E, att_src, att_dst, wt, o1, o2, o3, o4, o5);

  // CSR scan
  scan_deg<<<1, 1024, 0, stream>>>(deg, start, cursor, N);

  // fused: fill buckets + attention logits
  { int nbFill = (E + 255) / 256;
    int nbDots = (N + 15) / 16;
    fill_adots<<<nbFill + nbDots, 256, 0, stream>>>(ei, cursor, srcs, E, nbFill,
                                                    xb, wt, a_all, N); }

  // 2) GAT softmax + x-space aggregate -> aggb
  gat_aggregate<<<N, 256, 0, stream>>>(xb, a_all, start, deg, srcs, aggb, N);

  // 3) per-head GEMM (128x256, 8 waves): x1 = relu(agg @ W_hd + b_gat)
  { dim3 grid((N + 127) / 128, HEADS);
    gemm_gat<<<grid, 512, 0, stream>>>(aggb, WgatT, b_gat, x1b, N); }

  // 4) split-K SAGE GEMM (128x256, 8 waves) -> 2 bf16 partials
  { dim3 grid((N + 127) / 128, 512 / 256, KSPLIT);
    gemm_sage<<<grid, 512, 0, stream>>>(x1b, WsT, ypart, N, 512, GDIM, GDIM / KSPLIT); }

  // 5) fused SAGE mean-aggregate (over both partials) + MLP head -> out
  sage_mlp<<<(N + 15) / 16, 512, 0, stream>>>(ypart, (size_t)N * 512, start, deg, srcs, b_sage_l,
                                              W_lin1, b_lin1, W_lin2, b_lin2, out, N);
}